// Round 1
// baseline (3209.420 us; speedup 1.0000x reference)
//
#include <hip/hip_runtime.h>
#include <cstdint>
#include <cstddef>

// ---------------- problem dims ----------------
#define NB 4096   // batch
#define NE 768    // in features
#define NH 2048   // hidden
#define NKF 128   // GP feature dim
#define NC 200    // classes
#define NN 20     // inducing points per class
#define NITER 40  // power iterations

typedef __attribute__((ext_vector_type(8))) short s16x8;
typedef __attribute__((ext_vector_type(8))) unsigned short u16x8;
typedef __attribute__((ext_vector_type(4))) unsigned short u16x4;
typedef __attribute__((ext_vector_type(4))) float f32x4;

__device__ inline unsigned short f2bf(float x) {
  unsigned u = __builtin_bit_cast(unsigned, x);
  u += 0x7fffu + ((u >> 16) & 1u);
  return (unsigned short)(u >> 16);
}
__device__ inline float bf2f(unsigned short h) {
  return __builtin_bit_cast(float, (unsigned)h << 16);
}
__device__ inline float gelu_exact(float x) {
  return x * 0.5f * (1.0f + erff(x * 0.70710678118654752f));
}

// ---------------- workspace layout (bytes) ----------------
constexpr size_t SZ_W1BF = (size_t)NH * NE * 2;
constexpr size_t SZ_W2BF = (size_t)NH * NH * 2;
constexpr size_t SZ_WPBF = (size_t)NKF * NH * 2;
constexpr size_t SZ_SLOT = (size_t)NB * NH * 2;  // 16.8 MB

constexpr size_t OFF_W1BF = 0;
constexpr size_t OFF_W2BF = OFF_W1BF + SZ_W1BF;
constexpr size_t OFF_WPBF = OFF_W2BF + SZ_W2BF;
constexpr size_t OFF_XBF  = OFF_WPBF + SZ_WPBF;  // slot A: Xbf (LN1 out), later reused for H2bf
constexpr size_t OFF_H2BF = OFF_XBF;             // written by GEMM2 (after GEMM1 done with Xbf)
constexpr size_t OFF_H1BF = OFF_XBF + SZ_SLOT;   // gelu(GEMM1) bf16
constexpr size_t OFF_H1N  = OFF_H1BF + SZ_SLOT;  // LN2 out bf16
constexpr size_t OFF_HP   = OFF_H1N + SZ_SLOT;   // projection fp32 [NB][NKF]
constexpr size_t OFF_H2S  = OFF_HP + (size_t)NB * NKF * 4;  // |h|^2 per row
constexpr size_t OFF_PV   = OFF_H2S + (size_t)NB * 4;       // power-iter 3 mats x 3 bufs x 2048 f32
constexpr size_t OFF_SINV = OFF_PV + (size_t)3 * 3 * 2048 * 4;
constexpr size_t OFF_Z2   = OFF_SINV + 256;
constexpr size_t OFF_LC   = OFF_Z2 + (size_t)NC * NN * 4;
constexpr size_t OFF_AL   = OFF_LC + (size_t)NC * NN * NN * 4;
constexpr size_t WS_NEED  = OFF_AL + (size_t)NC * NN * 4;

// ==================== power iteration ====================
// pv layout: [mat 0..2][buf 0..2][2048] f32
__global__ __launch_bounds__(256) void init_power(float* __restrict__ pv) {
  int g = blockIdx.x * 256 + threadIdx.x;
  if (g < 3 * 3 * 2048) {
    int buf = (g / 2048) % 3;
    pv[g] = (buf == 0) ? 1.0f : 0.0f;
  }
}

// One iteration: v_hat = normalize(buf[iter%3]); t = W^T (W v_hat) accumulated
// atomically into buf[(iter+1)%3]; buf[(iter+2)%3] zeroed for next launch.
__global__ __launch_bounds__(256) void power_iter(const float* __restrict__ W1,
                                                  const float* __restrict__ W2,
                                                  const float* __restrict__ Wp,
                                                  float* __restrict__ pv, int iter) {
  int bx = blockIdx.x, t = threadIdx.x;
  int m, stripe, Kd;
  const float* W;
  if (bx < 32)      { m = 0; stripe = bx;      W = W1; Kd = NE; }
  else if (bx < 64) { m = 1; stripe = bx - 32; W = W2; Kd = NH; }
  else              { m = 2; stripe = bx - 64; W = Wp; Kd = NH; }

  const float* vbuf = pv + ((size_t)m * 3 + (iter % 3)) * 2048;
  float* wbuf = pv + ((size_t)m * 3 + ((iter + 1) % 3)) * 2048;

  // zero the buffer used two launches from now (nobody touches it this launch)
  {
    int gz = bx * 256 + t;
    if (gz < 3 * 2048) {
      int mm = gz / 2048, kk = gz % 2048;
      pv[((size_t)mm * 3 + ((iter + 2) % 3)) * 2048 + kk] = 0.0f;
    }
  }

  __shared__ float vs[2048];
  __shared__ float red[256];
  __shared__ float u[64];

  float s = 0.f;
  for (int k = t; k < Kd; k += 256) { float x = vbuf[k]; s += x * x; }
  red[t] = s;
  __syncthreads();
  if (t < 64) {
    float a = red[t] + red[t + 64] + red[t + 128] + red[t + 192];
    for (int off = 32; off; off >>= 1) a += __shfl_down(a, off);
    if (t == 0) red[0] = a;
  }
  __syncthreads();
  float rn = rsqrtf(red[0] + 1e-30f);
  for (int k = t; k < Kd; k += 256) vs[k] = vbuf[k] * rn;
  __syncthreads();

  // phase A: u = W_stripe * vs (64 rows, one row per wave per pass)
  int wid = t >> 6, lane = t & 63;
  int r0 = stripe * 64;
  for (int pass = 0; pass < 16; ++pass) {
    int rl = pass * 4 + wid;
    const float* wrow = W + (size_t)(r0 + rl) * Kd;
    float a = 0.f;
    for (int k = lane; k < Kd; k += 64) a += wrow[k] * vs[k];
    for (int off = 32; off; off >>= 1) a += __shfl_down(a, off);
    if (lane == 0) u[rl] = a;
  }
  __syncthreads();

  // phase B: t_k = sum_r W[r][k]*u[r] -> atomic into wbuf
  for (int k = t; k < Kd; k += 256) {
    float acc = 0.f;
    const float* wc = W + (size_t)r0 * Kd + k;
    #pragma unroll 8
    for (int r = 0; r < 64; ++r) acc += wc[(size_t)r * Kd] * u[r];
    atomicAdd(&wbuf[k], acc);
  }
}

__global__ __launch_bounds__(256) void finalize_sigma(const float* __restrict__ pv,
                                                      float* __restrict__ sinv) {
  int m = blockIdx.x, t = threadIdx.x;
  const float* tb = pv + ((size_t)m * 3 + (NITER % 3)) * 2048;
  __shared__ float red[256];
  float s = 0.f;
  for (int k = t; k < 2048; k += 256) { float x = tb[k]; s += x * x; }
  red[t] = s;
  __syncthreads();
  if (t == 0) {
    float a = 0.f;
    for (int i = 0; i < 256; ++i) a += red[i];
    // ||t|| = lambda_max(G) = sigma^2  ->  sigma = normsq^(1/4)
    sinv[m] = rsqrtf(sqrtf(a));
  }
}

__global__ __launch_bounds__(256) void scale_weights(const float* __restrict__ W1,
                                                     const float* __restrict__ W2,
                                                     const float* __restrict__ Wp,
                                                     const float* __restrict__ sinv,
                                                     unsigned short* __restrict__ W1bf,
                                                     unsigned short* __restrict__ W2bf,
                                                     unsigned short* __restrict__ Wpbf) {
  const int n1 = NH * NE, n2 = NH * NH;
  float s0 = sinv[0], s1 = sinv[1], s2 = sinv[2];
  int base = blockIdx.x * 2048;
  for (int i = threadIdx.x; i < 2048; i += 256) {
    int g = base + i;
    if (g < n1) {
      W1bf[g] = f2bf(W1[g] * s0);
    } else if (g < n1 + n2) {
      int q = g - n1; W2bf[q] = f2bf(W2[q] * s1);
    } else {
      int q = g - n1 - n2; Wpbf[q] = f2bf(Wp[q] * s2);
    }
  }
}

// ==================== layernorms ====================
// LN over 768 fp32, write bf16. one wave per row.
__global__ __launch_bounds__(256) void ln_e(const float* __restrict__ X,
                                            const float* __restrict__ g,
                                            const float* __restrict__ b,
                                            unsigned short* __restrict__ out) {
  int wid = threadIdx.x >> 6, lane = threadIdx.x & 63;
  int row = blockIdx.x * 4 + wid;
  const float* xr = X + (size_t)row * NE;
  float4 v[3];
  float s = 0.f, sq = 0.f;
  #pragma unroll
  for (int j = 0; j < 3; ++j) {
    v[j] = *(const float4*)(xr + j * 256 + lane * 4);
    s += v[j].x + v[j].y + v[j].z + v[j].w;
    sq += v[j].x * v[j].x + v[j].y * v[j].y + v[j].z * v[j].z + v[j].w * v[j].w;
  }
  for (int off = 32; off; off >>= 1) { s += __shfl_down(s, off); sq += __shfl_down(sq, off); }
  s = __shfl(s, 0); sq = __shfl(sq, 0);
  float mean = s * (1.0f / NE);
  float var = sq * (1.0f / NE) - mean * mean;
  float rstd = rsqrtf(var + 1e-5f);
  unsigned short* orow = out + (size_t)row * NE;
  #pragma unroll
  for (int j = 0; j < 3; ++j) {
    int e0 = j * 256 + lane * 4;
    float4 gg = *(const float4*)(g + e0);
    float4 bb = *(const float4*)(b + e0);
    u16x4 o;
    o[0] = f2bf((v[j].x - mean) * rstd * gg.x + bb.x);
    o[1] = f2bf((v[j].y - mean) * rstd * gg.y + bb.y);
    o[2] = f2bf((v[j].z - mean) * rstd * gg.z + bb.z);
    o[3] = f2bf((v[j].w - mean) * rstd * gg.w + bb.w);
    *(u16x4*)(orow + e0) = o;
  }
}

// LN over 2048 bf16 in, bf16 out. one wave per row.
__global__ __launch_bounds__(256) void ln_h(const unsigned short* __restrict__ X,
                                            const float* __restrict__ g,
                                            const float* __restrict__ b,
                                            unsigned short* __restrict__ out) {
  int wid = threadIdx.x >> 6, lane = threadIdx.x & 63;
  int row = blockIdx.x * 4 + wid;
  const unsigned short* xr = X + (size_t)row * NH;
  float xv[32];
  float s = 0.f, sq = 0.f;
  #pragma unroll
  for (int j = 0; j < 4; ++j) {
    u16x8 u = *(const u16x8*)(xr + j * 512 + lane * 8);
    #pragma unroll
    for (int q = 0; q < 8; ++q) {
      float x = bf2f(u[q]);
      xv[j * 8 + q] = x; s += x; sq += x * x;
    }
  }
  for (int off = 32; off; off >>= 1) { s += __shfl_down(s, off); sq += __shfl_down(sq, off); }
  s = __shfl(s, 0); sq = __shfl(sq, 0);
  float mean = s * (1.0f / NH);
  float var = sq * (1.0f / NH) - mean * mean;
  float rstd = rsqrtf(var + 1e-5f);
  unsigned short* orow = out + (size_t)row * NH;
  #pragma unroll
  for (int j = 0; j < 4; ++j) {
    int e0 = j * 512 + lane * 8;
    float4 ga = *(const float4*)(g + e0);
    float4 gb = *(const float4*)(g + e0 + 4);
    float4 ba = *(const float4*)(b + e0);
    float4 bb = *(const float4*)(b + e0 + 4);
    u16x8 o;
    o[0] = f2bf((xv[j*8+0] - mean) * rstd * ga.x + ba.x);
    o[1] = f2bf((xv[j*8+1] - mean) * rstd * ga.y + ba.y);
    o[2] = f2bf((xv[j*8+2] - mean) * rstd * ga.z + ba.z);
    o[3] = f2bf((xv[j*8+3] - mean) * rstd * ga.w + ba.w);
    o[4] = f2bf((xv[j*8+4] - mean) * rstd * gb.x + bb.x);
    o[5] = f2bf((xv[j*8+5] - mean) * rstd * gb.y + bb.y);
    o[6] = f2bf((xv[j*8+6] - mean) * rstd * gb.z + bb.z);
    o[7] = f2bf((xv[j*8+7] - mean) * rstd * gb.w + bb.w);
    *(u16x8*)(orow + e0) = o;
  }
}

// ==================== bf16 MFMA GEMM (NT): C = A[M,K] * B[N,K]^T ====================
// 128x128 tile, BK=32, 4 waves (2x2), each wave 4x4 fragments of 16x16x32.
// EPI 0: x = gelu(acc + bias[col]) -> bf16 store.  EPI 1: atomicAdd fp32 (split-K).
#define LSS 40  // LDS row stride in shorts (32 + 8 pad -> 16B aligned, 2-way-bank only)

template <int EPI>
__global__ __launch_bounds__(256) void gemm_nt(const unsigned short* __restrict__ A,
                                               const unsigned short* __restrict__ Bm,
                                               const float* __restrict__ bias,
                                               void* __restrict__ Cout,
                                               int M, int Nn, int Kk, int KCH) {
  __shared__ unsigned short As[128 * LSS];
  __shared__ unsigned short Bs[128 * LSS];
  int t = threadIdx.x;
  int bm0 = blockIdx.x * 128, bn0 = blockIdx.y * 128;
  int wid = t >> 6, lane = t & 63;
  int wm = wid >> 1, wn = wid & 1;

  int kb = 0, ke = Kk;
  if (KCH > 0) { kb = blockIdx.z * KCH; ke = kb + KCH; }

  f32x4 acc[4][4] = {};

  int lrow = t >> 2;         // 0..63
  int lk8 = (t & 3) * 8;     // 0,8,16,24
  const unsigned short* Ag = A + (size_t)(bm0 + lrow) * Kk + lk8;
  const unsigned short* Bg = Bm + (size_t)(bn0 + lrow) * Kk + lk8;

  int arow = wm * 64 + (lane & 15);
  int brow = wn * 64 + (lane & 15);
  int kfr = (lane >> 4) * 8;

  for (int ks = kb; ks < ke; ks += 32) {
    u16x8 ra0 = *(const u16x8*)(Ag + ks);
    u16x8 ra1 = *(const u16x8*)(Ag + (size_t)64 * Kk + ks);
    u16x8 rb0 = *(const u16x8*)(Bg + ks);
    u16x8 rb1 = *(const u16x8*)(Bg + (size_t)64 * Kk + ks);
    __syncthreads();
    *(u16x8*)&As[lrow * LSS + lk8] = ra0;
    *(u16x8*)&As[(lrow + 64) * LSS + lk8] = ra1;
    *(u16x8*)&Bs[lrow * LSS + lk8] = rb0;
    *(u16x8*)&Bs[(lrow + 64) * LSS + lk8] = rb1;
    __syncthreads();
    s16x8 af[4], bfr[4];
    #pragma unroll
    for (int i = 0; i < 4; ++i) af[i] = *(const s16x8*)&As[(arow + i * 16) * LSS + kfr];
    #pragma unroll
    for (int j = 0; j < 4; ++j) bfr[j] = *(const s16x8*)&Bs[(brow + j * 16) * LSS + kfr];
    #pragma unroll
    for (int i = 0; i < 4; ++i)
      #pragma unroll
      for (int j = 0; j < 4; ++j)
        acc[i][j] = __builtin_amdgcn_mfma_f32_16x16x32_bf16(af[i], bfr[j], acc[i][j], 0, 0, 0);
  }

  // epilogue: D row = (lane>>4)*4 + reg, col = lane&15 (guide-verified layout)
  int crow0 = bm0 + wm * 64 + (lane >> 4) * 4;
  int ccol0 = bn0 + wn * 64 + (lane & 15);
  if constexpr (EPI == 0) {
    unsigned short* C = (unsigned short*)Cout;
    #pragma unroll
    for (int i = 0; i < 4; ++i) {
      #pragma unroll
      for (int j = 0; j < 4; ++j) {
        int col = ccol0 + j * 16;
        float bb = bias[col];
        #pragma unroll
        for (int r = 0; r < 4; ++r) {
          int row = crow0 + i * 16 + r;
          float x = acc[i][j][r] + bb;
          C[(size_t)row * Nn + col] = f2bf(gelu_exact(x));
        }
      }
    }
  } else {
    float* C = (float*)Cout;
    #pragma unroll
    for (int i = 0; i < 4; ++i)
      #pragma unroll
      for (int j = 0; j < 4; ++j) {
        int col = ccol0 + j * 16;
        #pragma unroll
        for (int r = 0; r < 4; ++r) {
          int row = crow0 + i * 16 + r;
          atomicAdd(&C[(size_t)row * Nn + col], acc[i][j][r]);
        }
      }
  }
}

// add bias, compute |h|^2 per row, rewrite Hp. one wave per row.
__global__ __launch_bounds__(256) void finish_proj(float* __restrict__ Hp,
                                                   const float* __restrict__ bp,
                                                   float* __restrict__ h2) {
  int wid = threadIdx.x >> 6, lane = threadIdx.x & 63;
  int row = blockIdx.x * 4 + wid;
  float* r = Hp + (size_t)row * NKF;
  float x0 = r[lane] + bp[lane];
  float x1 = r[lane + 64] + bp[lane + 64];
  float s = x0 * x0 + x1 * x1;
  for (int off = 32; off; off >>= 1) s += __shfl_down(s, off);
  r[lane] = x0;
  r[lane + 64] = x1;
  if (lane == 0) h2[row] = s;
}

// ==================== GP prep: z2, k_zz Cholesky, alpha ====================
__global__ __launch_bounds__(128) void gp_prep(const float* __restrict__ z,
                                               const float* __restrict__ vm,
                                               const float* __restrict__ ll,
                                               float* __restrict__ z2g,
                                               float* __restrict__ Lg,
                                               float* __restrict__ alphag) {
  int c = blockIdx.x, t = threadIdx.x;
  __shared__ float zc[NN * NKF];
  __shared__ float Amat[NN][NN + 1];
  __shared__ float z2s[NN], ys[NN], al[NN];
  const float* zcg = z + (size_t)c * NN * NKF;
  for (int i = t; i < NN * NKF; i += 128) zc[i] = zcg[i];
  __syncthreads();
  if (t < NN) {
    float s = 0.f;
    for (int k = 0; k < NKF; ++k) { float v = zc[t * NKF + k]; s += v * v; }
    z2s[t] = s;
    z2g[c * NN + t] = s;
  }
  __syncthreads();
  float inv2 = 0.5f * expf(-2.0f * ll[0]);  // 1/(2*ls^2)
  for (int e = t; e < NN * NN; e += 128) {
    int n = e / NN, m = e % NN;
    float d = 0.f;
    for (int k = 0; k < NKF; ++k) d += zc[n * NKF + k] * zc[m * NKF + k];
    float d2 = fmaxf(z2s[n] + z2s[m] - 2.0f * d, 0.0f);
    float v = expf(-d2 * inv2);
    if (n == m) v += 1e-4f;
    Amat[n][m] = v;
  }
  __syncthreads();
  // in-place Cholesky (lower)
  for (int j = 0; j < NN; ++j) {
    if (t == 0) {
      float s = Amat[j][j];
      for (int p = 0; p < j; ++p) s -= Amat[j][p] * Amat[j][p];
      Amat[j][j] = sqrtf(s);
    }
    __syncthreads();
    if (t > j && t < NN) {
      float s = Amat[t][j];
      for (int p = 0; p < j; ++p) s -= Amat[t][p] * Amat[j][p];
      Amat[t][j] = s / Amat[j][j];
    }
    __syncthreads();
  }
  if (t == 0) {
    const float* mc = vm + c * NN;
    for (int n = 0; n < NN; ++n) {
      float s = mc[n];
      for (int m = 0; m < n; ++m) s -= Amat[n][m] * ys[m];
      ys[n] = s / Amat[n][n];
    }
    for (int n = NN - 1; n >= 0; --n) {
      float s = ys[n];
      for (int m = n + 1; m < NN; ++m) s -= Amat[m][n] * al[m];
      al[n] = s / Amat[n][n];
    }
  }
  __syncthreads();
  for (int e = t; e < NN * NN; e += 128) {
    int n = e / NN, m = e % NN;
    Lg[(size_t)c * NN * NN + e] = (m <= n) ? Amat[n][m] : 0.0f;
  }
  if (t < NN) alphag[c * NN + t] = al[t];
}

// ==================== GP main: logits + uncertainty ====================
__global__ __launch_bounds__(256) void gp_main(const float* __restrict__ Hp,
                                               const float* __restrict__ h2g,
                                               const float* __restrict__ z,
                                               const float* __restrict__ z2g,
                                               const float* __restrict__ Lg,
                                               const float* __restrict__ alphag,
                                               const float* __restrict__ ll,
                                               float* __restrict__ logits,
                                               float* __restrict__ unc) {
  int c = blockIdx.y, b0 = blockIdx.x * 256, t = threadIdx.x;
  __shared__ float zc[NN * NKF];
  __shared__ float Ls[NN][NN + 1];
  __shared__ float z2s[NN], al[NN];
  __shared__ float hch[256][17];
  for (int i = t; i < NN * NKF; i += 256) zc[i] = z[(size_t)c * NN * NKF + i];
  for (int i = t; i < NN * NN; i += 256) {
    int n = i / NN, m = i % NN;
    Ls[n][m] = Lg[(size_t)c * NN * NN + i];
  }
  if (t < NN) { z2s[t] = z2g[c * NN + t]; al[t] = alphag[c * NN + t]; }
  float inv2 = 0.5f * expf(-2.0f * ll[0]);
  float acc[NN];
  #pragma unroll
  for (int n = 0; n < NN; ++n) acc[n] = 0.f;

  for (int kc = 0; kc < 8; ++kc) {
    int k0 = kc * 16;
    __syncthreads();
    #pragma unroll
    for (int p = 0; p < 16; ++p) {
      int rr = p * 16 + (t >> 4);
      int cc = t & 15;
      hch[rr][cc] = Hp[(size_t)(b0 + rr) * NKF + k0 + cc];
    }
    __syncthreads();
    float hk[16];
    #pragma unroll
    for (int kk = 0; kk < 16; ++kk) hk[kk] = hch[t][kk];
    #pragma unroll
    for (int n = 0; n < NN; ++n) {
      float s = acc[n];
      const float* zr = &zc[n * NKF + k0];
      #pragma unroll
      for (int kk = 0; kk < 16; ++kk) s += hk[kk] * zr[kk];
      acc[n] = s;
    }
  }

  float h2b = h2g[b0 + t];
  float lg = 0.f;
  #pragma unroll
  for (int n = 0; n < NN; ++n) {
    float d2 = fmaxf(h2b + z2s[n] - 2.0f * acc[n], 0.0f);
    float kx = expf(-d2 * inv2);
    acc[n] = kx;
    lg += kx * al[n];
  }
  logits[(size_t)(b0 + t) * NC + c] = lg;

  // forward triangular solve v = L^-1 k, in place
  float vsum = 0.f;
  #pragma unroll
  for (int n = 0; n < NN; ++n) {
    float s = acc[n];
    #pragma unroll
    for (int m = 0; m < NN; ++m) {
      if (m < n) s -= Ls[n][m] * acc[m];
    }
    s /= Ls[n][n];
    acc[n] = s;
    vsum += s * s;
  }
  atomicAdd(&unc[b0 + t], fmaxf(1.0f - vsum, 0.0f) * (1.0f / NC));
}

// ==================== softmax over classes ====================
__global__ __launch_bounds__(256) void softmax_k(const float* __restrict__ logits,
                                                 float* __restrict__ probs) {
  int wid = threadIdx.x >> 6, lane = threadIdx.x & 63;
  int row = blockIdx.x * 4 + wid;
  const float* lr = logits + (size_t)row * NC;
  float x[4];
  float mx = -1e30f;
  #pragma unroll
  for (int j = 0; j < 4; ++j) {
    int cix = lane + j * 64;
    x[j] = (cix < NC) ? lr[cix] : -1e30f;
    mx = fmaxf(mx, x[j]);
  }
  for (int off = 32; off; off >>= 1) mx = fmaxf(mx, __shfl_xor(mx, off));
  float s = 0.f;
  #pragma unroll
  for (int j = 0; j < 4; ++j) {
    int cix = lane + j * 64;
    float e = (cix < NC) ? expf(x[j] - mx) : 0.0f;
    x[j] = e; s += e;
  }
  for (int off = 32; off; off >>= 1) s += __shfl_xor(s, off);
  float inv = 1.0f / s;
  float* pr = probs + (size_t)row * NC;
  #pragma unroll
  for (int j = 0; j < 4; ++j) {
    int cix = lane + j * 64;
    if (cix < NC) pr[cix] = x[j] * inv;
  }
}

// ==================== launch ====================
extern "C" void kernel_launch(void* const* d_in, const int* in_sizes, int n_in,
                              void* d_out, int out_size, void* d_ws, size_t ws_size,
                              hipStream_t stream) {
  if (ws_size < WS_NEED) return;  // workspace too small; signal via failed output

  const float* X   = (const float*)d_in[0];
  const float* g1  = (const float*)d_in[1];
  const float* be1 = (const float*)d_in[2];
  const float* W1  = (const float*)d_in[3];
  const float* b1  = (const float*)d_in[4];
  const float* g2  = (const float*)d_in[5];
  const float* be2 = (const float*)d_in[6];
  const float* W2  = (const float*)d_in[7];
  const float* b2  = (const float*)d_in[8];
  const float* Wp  = (const float*)d_in[9];
  const float* bp  = (const float*)d_in[10];
  const float* ll  = (const float*)d_in[11];
  const float* Z   = (const float*)d_in[12];
  const float* VM  = (const float*)d_in[13];

  char* ws = (char*)d_ws;
  unsigned short* W1bf = (unsigned short*)(ws + OFF_W1BF);
  unsigned short* W2bf = (unsigned short*)(ws + OFF_W2BF);
  unsigned short* Wpbf = (unsigned short*)(ws + OFF_WPBF);
  unsigned short* Xbf  = (unsigned short*)(ws + OFF_XBF);
  unsigned short* H2bf = (unsigned short*)(ws + OFF_H2BF);
  unsigned short* H1bf = (unsigned short*)(ws + OFF_H1BF);
  unsigned short* H1n  = (unsigned short*)(ws + OFF_H1N);
  float* Hp    = (float*)(ws + OFF_HP);
  float* h2s   = (float*)(ws + OFF_H2S);
  float* pv    = (float*)(ws + OFF_PV);
  float* sinv  = (float*)(ws + OFF_SINV);
  float* z2g   = (float*)(ws + OFF_Z2);
  float* Lg    = (float*)(ws + OFF_LC);
  float* alphag= (float*)(ws + OFF_AL);

  float* out    = (float*)d_out;
  float* logits = out + (size_t)NB * NC;
  float* unc    = out + (size_t)2 * NB * NC;

  hipMemsetAsync(Hp, 0, (size_t)NB * NKF * 4, stream);
  hipMemsetAsync(unc, 0, (size_t)NB * 4, stream);

  // spectral norms via power iteration (3 matrices in one grid)
  init_power<<<dim3(72), 256, 0, stream>>>(pv);
  for (int i = 0; i < NITER; ++i)
    power_iter<<<dim3(66), 256, 0, stream>>>(W1, W2, Wp, pv, i);
  finalize_sigma<<<dim3(3), 256, 0, stream>>>(pv, sinv);
  scale_weights<<<dim3(2944), 256, 0, stream>>>(W1, W2, Wp, sinv, W1bf, W2bf, Wpbf);

  // MLP
  ln_e<<<dim3(NB / 4), 256, 0, stream>>>(X, g1, be1, Xbf);
  gemm_nt<0><<<dim3(NB / 128, NH / 128), 256, 0, stream>>>(Xbf, W1bf, b1, (void*)H1bf, NB, NH, NE, 0);
  ln_h<<<dim3(NB / 4), 256, 0, stream>>>(H1bf, g2, be2, H1n);
  gemm_nt<0><<<dim3(NB / 128, NH / 128), 256, 0, stream>>>(H1n, W2bf, b2, (void*)H2bf, NB, NH, NH, 0);
  gemm_nt<1><<<dim3(NB / 128, 1, 8), 256, 0, stream>>>(H2bf, Wpbf, bp, (void*)Hp, NB, NKF, NH, NH / 8);
  finish_proj<<<dim3(NB / 4), 256, 0, stream>>>(Hp, bp, h2s);

  // GP head
  gp_prep<<<dim3(NC), 128, 0, stream>>>(Z, VM, ll, z2g, Lg, alphag);
  gp_main<<<dim3(NB / 256, NC), 256, 0, stream>>>(Hp, h2s, Z, z2g, Lg, alphag, ll, logits, unc);
  softmax_k<<<dim3(NB / 4), 256, 0, stream>>>(logits, out);
}

// Round 2
// 1394.375 us; speedup vs baseline: 2.3017x; 2.3017x over previous
//
#include <hip/hip_runtime.h>
#include <cstdint>
#include <cstddef>

// ---------------- problem dims ----------------
#define NB 4096   // batch
#define NE 768    // in features
#define NH 2048   // hidden
#define NKF 128   // GP feature dim
#define NC 200    // classes
#define NN 20     // inducing points per class
#define NITER 40  // power iterations

typedef __attribute__((ext_vector_type(8))) short s16x8;
typedef __attribute__((ext_vector_type(8))) unsigned short u16x8;
typedef __attribute__((ext_vector_type(4))) unsigned short u16x4;
typedef __attribute__((ext_vector_type(4))) float f32x4;

__device__ inline unsigned short f2bf(float x) {
  unsigned u = __builtin_bit_cast(unsigned, x);
  u += 0x7fffu + ((u >> 16) & 1u);
  return (unsigned short)(u >> 16);
}
__device__ inline float bf2f(unsigned short h) {
  return __builtin_bit_cast(float, (unsigned)h << 16);
}
__device__ inline float gelu_exact(float x) {
  return x * 0.5f * (1.0f + erff(x * 0.70710678118654752f));
}

// ---------------- workspace layout (bytes) ----------------
constexpr size_t SZ_W1BF = (size_t)NH * NE * 2;
constexpr size_t SZ_W2BF = (size_t)NH * NH * 2;
constexpr size_t SZ_WPBF = (size_t)NKF * NH * 2;
constexpr size_t SZ_SLOT = (size_t)NB * NH * 2;  // 16.8 MB

constexpr size_t OFF_W1BF = 0;
constexpr size_t OFF_W2BF = OFF_W1BF + SZ_W1BF;
constexpr size_t OFF_WPBF = OFF_W2BF + SZ_W2BF;
constexpr size_t OFF_XBF  = OFF_WPBF + SZ_WPBF;  // slot A: Xbf (LN1 out), later reused for H2bf
constexpr size_t OFF_H2BF = OFF_XBF;             // written by GEMM2 (after GEMM1 done with Xbf)
constexpr size_t OFF_H1BF = OFF_XBF + SZ_SLOT;   // gelu(GEMM1) bf16
constexpr size_t OFF_H1N  = OFF_H1BF + SZ_SLOT;  // LN2 out bf16
constexpr size_t OFF_HP   = OFF_H1N + SZ_SLOT;   // projection fp32 [NB][NKF]
constexpr size_t OFF_H2S  = OFF_HP + (size_t)NB * NKF * 4;  // |h|^2 per row
constexpr size_t OFF_PV   = OFF_H2S + (size_t)NB * 4;       // power-iter vectors + norm slots
constexpr size_t OFF_SINV = OFF_PV + (size_t)3 * 3 * 2048 * 4;
constexpr size_t OFF_Z2   = OFF_SINV + 256;
constexpr size_t OFF_LC   = OFF_Z2 + (size_t)NC * NN * 4;
constexpr size_t OFF_AL   = OFF_LC + (size_t)NC * NN * NN * 4;
constexpr size_t WS_NEED  = OFF_AL + (size_t)NC * NN * 4;

// Gram-phase scratch aliased into the activation slots (used strictly BEFORE
// ln_e/gemm1/ln_h write them; stream order guarantees safety):
//   XBF slot : W1T bf16 [768][2048] | G1 f32 [768][768] | Wpbf0 bf16 [128][2048] | Gp f32 [128][128]
//   H1BF slot: W2T bf16 [2048][2048]
//   H1N slot : G2 f32 [2048][2048]  (exactly 16.8 MB)
constexpr size_t GOFF_W1T = OFF_XBF;
constexpr size_t GOFF_G1  = GOFF_W1T + (size_t)NE * NH * 2;       // +3,145,728
constexpr size_t GOFF_WP0 = GOFF_G1 + (size_t)NE * NE * 4;        // +2,359,296
constexpr size_t GOFF_GP  = GOFF_WP0 + (size_t)NKF * NH * 2;      // +524,288
constexpr size_t GOFF_W2T = OFF_H1BF;
constexpr size_t GOFF_G2  = OFF_H1N;
static_assert(GOFF_GP + (size_t)NKF * NKF * 4 <= OFF_XBF + SZ_SLOT, "gram scratch overflow");

// ==================== elementwise fp32 -> bf16 cast (Wp) ====================
__global__ __launch_bounds__(256) void cast_bf(const float* __restrict__ in,
                                               unsigned short* __restrict__ out, int n) {
  for (int i = blockIdx.x * 256 + threadIdx.x; i < n; i += gridDim.x * 256)
    out[i] = f2bf(in[i]);
}

// ==================== transpose+cast: fp32 [R][C] -> bf16 [C][R] ====================
__global__ __launch_bounds__(256) void transpose_cast(const float* __restrict__ in,
                                                      unsigned short* __restrict__ out,
                                                      int R, int C) {
  __shared__ float tile[64][65];
  int c0 = blockIdx.x * 64, r0 = blockIdx.y * 64;
  int tx = threadIdx.x & 63, ty = threadIdx.x >> 6;  // ty 0..3
  #pragma unroll
  for (int j = 0; j < 16; ++j) {
    int r = ty + j * 4;
    tile[r][tx] = in[(size_t)(r0 + r) * C + c0 + tx];
  }
  __syncthreads();
  #pragma unroll
  for (int j = 0; j < 16; ++j) {
    int cc = ty + j * 4;  // column index within tile
    out[(size_t)(c0 + cc) * R + r0 + tx] = f2bf(tile[tx][cc]);
  }
}

// ==================== Gram power iteration ====================
// vb: [3 mats][2 ping-pong][2048] f32 ; slots: [3][64] f32 (||v_i||^2 per iter)
__global__ __launch_bounds__(256) void init_gram(float* __restrict__ vb,
                                                 float* __restrict__ slots) {
  int t = threadIdx.x;
  for (int i = t; i < 3 * 2 * 2048; i += 256) vb[i] = 0.0f;
  __syncthreads();
  const int kd[3] = {NE, NH, NKF};
  for (int m = 0; m < 3; ++m)
    for (int k = t; k < kd[m]; k += 256) vb[(m * 2 + 0) * 2048 + k] = 1.0f;
  for (int i = t; i < 3 * 64; i += 256) slots[i] = 0.0f;
  __syncthreads();
  if (t < 3) slots[t * 64 + 0] = (float)kd[t];
}

// One iteration: v_hat = vb[iter&1]*rsqrt(slots[iter]); vb[(iter+1)&1] = G v_hat;
// ||out||^2 atomically accumulated into slots[iter+1] (pre-zeroed by init_gram).
// Block->rows ownership is fixed: no cross-block races on vout.
__global__ __launch_bounds__(256) void gram_iter(const float* __restrict__ G1,
                                                 const float* __restrict__ G2,
                                                 const float* __restrict__ Gp,
                                                 float* __restrict__ vb,
                                                 float* __restrict__ slots, int iter) {
  int b = blockIdx.x, t = threadIdx.x;
  int m, r0, Kd;
  const float* G;
  if (b < 96)       { m = 0; G = G1; Kd = NE;  r0 = b * 8; }
  else if (b < 352) { m = 1; G = G2; Kd = NH;  r0 = (b - 96) * 8; }
  else              { m = 2; G = Gp; Kd = NKF; r0 = (b - 352) * 8; }

  const float* vin = vb + ((size_t)m * 2 + (iter & 1)) * 2048;
  float* vout      = vb + ((size_t)m * 2 + ((iter + 1) & 1)) * 2048;
  float rn = rsqrtf(slots[m * 64 + iter]);

  __shared__ float vs[2048];
  for (int k = t; k < Kd; k += 256) vs[k] = vin[k] * rn;
  __syncthreads();

  int w = t >> 6, lane = t & 63;
  float nrm = 0.f;
  #pragma unroll
  for (int rr = 0; rr < 2; ++rr) {
    int row = r0 + w * 2 + rr;
    const float* gr = G + (size_t)row * Kd;
    float s = 0.f;
    for (int k = lane; k < Kd; k += 64) s += gr[k] * vs[k];
    for (int off = 32; off; off >>= 1) s += __shfl_down(s, off);
    if (lane == 0) { vout[row] = s; nrm += s * s; }
  }
  if (lane == 0) atomicAdd(&slots[m * 64 + iter + 1], nrm);
}

__global__ void finalize_sigma(const float* __restrict__ slots, float* __restrict__ sinv) {
  int m = threadIdx.x;
  // slots[m][NITER] = ||G v_hat||^2 = lambda_max^2 = sigma^4  ->  sinv = slots^(-1/4)
  if (m < 3) sinv[m] = rsqrtf(sqrtf(slots[m * 64 + NITER]));
}

__global__ __launch_bounds__(256) void scale_weights(const float* __restrict__ W1,
                                                     const float* __restrict__ W2,
                                                     const float* __restrict__ Wp,
                                                     const float* __restrict__ sinv,
                                                     unsigned short* __restrict__ W1bf,
                                                     unsigned short* __restrict__ W2bf,
                                                     unsigned short* __restrict__ Wpbf) {
  const int n1 = NH * NE, n2 = NH * NH;
  float s0 = sinv[0], s1 = sinv[1], s2 = sinv[2];
  int base = blockIdx.x * 2048;
  for (int i = threadIdx.x; i < 2048; i += 256) {
    int g = base + i;
    if (g < n1) {
      W1bf[g] = f2bf(W1[g] * s0);
    } else if (g < n1 + n2) {
      int q = g - n1; W2bf[q] = f2bf(W2[q] * s1);
    } else {
      int q = g - n1 - n2; Wpbf[q] = f2bf(Wp[q] * s2);
    }
  }
}

// ==================== layernorms ====================
// LN over 768 fp32, write bf16. one wave per row.
__global__ __launch_bounds__(256) void ln_e(const float* __restrict__ X,
                                            const float* __restrict__ g,
                                            const float* __restrict__ b,
                                            unsigned short* __restrict__ out) {
  int wid = threadIdx.x >> 6, lane = threadIdx.x & 63;
  int row = blockIdx.x * 4 + wid;
  const float* xr = X + (size_t)row * NE;
  float4 v[3];
  float s = 0.f, sq = 0.f;
  #pragma unroll
  for (int j = 0; j < 3; ++j) {
    v[j] = *(const float4*)(xr + j * 256 + lane * 4);
    s += v[j].x + v[j].y + v[j].z + v[j].w;
    sq += v[j].x * v[j].x + v[j].y * v[j].y + v[j].z * v[j].z + v[j].w * v[j].w;
  }
  for (int off = 32; off; off >>= 1) { s += __shfl_down(s, off); sq += __shfl_down(sq, off); }
  s = __shfl(s, 0); sq = __shfl(sq, 0);
  float mean = s * (1.0f / NE);
  float var = sq * (1.0f / NE) - mean * mean;
  float rstd = rsqrtf(var + 1e-5f);
  unsigned short* orow = out + (size_t)row * NE;
  #pragma unroll
  for (int j = 0; j < 3; ++j) {
    int e0 = j * 256 + lane * 4;
    float4 gg = *(const float4*)(g + e0);
    float4 bb = *(const float4*)(b + e0);
    u16x4 o;
    o[0] = f2bf((v[j].x - mean) * rstd * gg.x + bb.x);
    o[1] = f2bf((v[j].y - mean) * rstd * gg.y + bb.y);
    o[2] = f2bf((v[j].z - mean) * rstd * gg.z + bb.z);
    o[3] = f2bf((v[j].w - mean) * rstd * gg.w + bb.w);
    *(u16x4*)(orow + e0) = o;
  }
}

// LN over 2048 bf16 in, bf16 out. one wave per row.
__global__ __launch_bounds__(256) void ln_h(const unsigned short* __restrict__ X,
                                            const float* __restrict__ g,
                                            const float* __restrict__ b,
                                            unsigned short* __restrict__ out) {
  int wid = threadIdx.x >> 6, lane = threadIdx.x & 63;
  int row = blockIdx.x * 4 + wid;
  const unsigned short* xr = X + (size_t)row * NH;
  float xv[32];
  float s = 0.f, sq = 0.f;
  #pragma unroll
  for (int j = 0; j < 4; ++j) {
    u16x8 u = *(const u16x8*)(xr + j * 512 + lane * 8);
    #pragma unroll
    for (int q = 0; q < 8; ++q) {
      float x = bf2f(u[q]);
      xv[j * 8 + q] = x; s += x; sq += x * x;
    }
  }
  for (int off = 32; off; off >>= 1) { s += __shfl_down(s, off); sq += __shfl_down(sq, off); }
  s = __shfl(s, 0); sq = __shfl(sq, 0);
  float mean = s * (1.0f / NH);
  float var = sq * (1.0f / NH) - mean * mean;
  float rstd = rsqrtf(var + 1e-5f);
  unsigned short* orow = out + (size_t)row * NH;
  #pragma unroll
  for (int j = 0; j < 4; ++j) {
    int e0 = j * 512 + lane * 8;
    float4 ga = *(const float4*)(g + e0);
    float4 gb = *(const float4*)(g + e0 + 4);
    float4 ba = *(const float4*)(b + e0);
    float4 bb = *(const float4*)(b + e0 + 4);
    u16x8 o;
    o[0] = f2bf((xv[j*8+0] - mean) * rstd * ga.x + ba.x);
    o[1] = f2bf((xv[j*8+1] - mean) * rstd * ga.y + ba.y);
    o[2] = f2bf((xv[j*8+2] - mean) * rstd * ga.z + ba.z);
    o[3] = f2bf((xv[j*8+3] - mean) * rstd * ga.w + ba.w);
    o[4] = f2bf((xv[j*8+4] - mean) * rstd * gb.x + bb.x);
    o[5] = f2bf((xv[j*8+5] - mean) * rstd * gb.y + bb.y);
    o[6] = f2bf((xv[j*8+6] - mean) * rstd * gb.z + bb.z);
    o[7] = f2bf((xv[j*8+7] - mean) * rstd * gb.w + bb.w);
    *(u16x8*)(orow + e0) = o;
  }
}

// ==================== bf16 MFMA GEMM (NT): C = A[M,K] * B[N,K]^T ====================
// 128x128 tile, BK=32, 4 waves (2x2), each wave 4x4 fragments of 16x16x32.
// EPI 0: gelu(acc+bias) -> bf16.  EPI 1: atomicAdd fp32 (split-K).  EPI 2: plain fp32.
#define LSS 40  // LDS row stride in shorts

template <int EPI>
__global__ __launch_bounds__(256) void gemm_nt(const unsigned short* __restrict__ A,
                                               const unsigned short* __restrict__ Bm,
                                               const float* __restrict__ bias,
                                               void* __restrict__ Cout,
                                               int M, int Nn, int Kk, int KCH) {
  __shared__ unsigned short As[128 * LSS];
  __shared__ unsigned short Bs[128 * LSS];
  int t = threadIdx.x;
  int bm0 = blockIdx.x * 128, bn0 = blockIdx.y * 128;
  int wid = t >> 6, lane = t & 63;
  int wm = wid >> 1, wn = wid & 1;

  int kb = 0, ke = Kk;
  if (KCH > 0) { kb = blockIdx.z * KCH; ke = kb + KCH; }

  f32x4 acc[4][4] = {};

  int lrow = t >> 2;         // 0..63
  int lk8 = (t & 3) * 8;     // 0,8,16,24
  const unsigned short* Ag = A + (size_t)(bm0 + lrow) * Kk + lk8;
  const unsigned short* Bg = Bm + (size_t)(bn0 + lrow) * Kk + lk8;

  int arow = wm * 64 + (lane & 15);
  int brow = wn * 64 + (lane & 15);
  int kfr = (lane >> 4) * 8;

  for (int ks = kb; ks < ke; ks += 32) {
    u16x8 ra0 = *(const u16x8*)(Ag + ks);
    u16x8 ra1 = *(const u16x8*)(Ag + (size_t)64 * Kk + ks);
    u16x8 rb0 = *(const u16x8*)(Bg + ks);
    u16x8 rb1 = *(const u16x8*)(Bg + (size_t)64 * Kk + ks);
    __syncthreads();
    *(u16x8*)&As[lrow * LSS + lk8] = ra0;
    *(u16x8*)&As[(lrow + 64) * LSS + lk8] = ra1;
    *(u16x8*)&Bs[lrow * LSS + lk8] = rb0;
    *(u16x8*)&Bs[(lrow + 64) * LSS + lk8] = rb1;
    __syncthreads();
    s16x8 af[4], bfr[4];
    #pragma unroll
    for (int i = 0; i < 4; ++i) af[i] = *(const s16x8*)&As[(arow + i * 16) * LSS + kfr];
    #pragma unroll
    for (int j = 0; j < 4; ++j) bfr[j] = *(const s16x8*)&Bs[(brow + j * 16) * LSS + kfr];
    #pragma unroll
    for (int i = 0; i < 4; ++i)
      #pragma unroll
      for (int j = 0; j < 4; ++j)
        acc[i][j] = __builtin_amdgcn_mfma_f32_16x16x32_bf16(af[i], bfr[j], acc[i][j], 0, 0, 0);
  }

  // epilogue: D row = (lane>>4)*4 + reg, col = lane&15
  int crow0 = bm0 + wm * 64 + (lane >> 4) * 4;
  int ccol0 = bn0 + wn * 64 + (lane & 15);
  if constexpr (EPI == 0) {
    unsigned short* C = (unsigned short*)Cout;
    #pragma unroll
    for (int i = 0; i < 4; ++i) {
      #pragma unroll
      for (int j = 0; j < 4; ++j) {
        int col = ccol0 + j * 16;
        float bb = bias[col];
        #pragma unroll
        for (int r = 0; r < 4; ++r) {
          int row = crow0 + i * 16 + r;
          float x = acc[i][j][r] + bb;
          C[(size_t)row * Nn + col] = f2bf(gelu_exact(x));
        }
      }
    }
  } else if constexpr (EPI == 1) {
    float* C = (float*)Cout;
    #pragma unroll
    for (int i = 0; i < 4; ++i)
      #pragma unroll
      for (int j = 0; j < 4; ++j) {
        int col = ccol0 + j * 16;
        #pragma unroll
        for (int r = 0; r < 4; ++r) {
          int row = crow0 + i * 16 + r;
          atomicAdd(&C[(size_t)row * Nn + col], acc[i][j][r]);
        }
      }
  } else {
    float* C = (float*)Cout;
    #pragma unroll
    for (int i = 0; i < 4; ++i)
      #pragma unroll
      for (int j = 0; j < 4; ++j) {
        int col = ccol0 + j * 16;
        #pragma unroll
        for (int r = 0; r < 4; ++r) {
          int row = crow0 + i * 16 + r;
          C[(size_t)row * Nn + col] = acc[i][j][r];
        }
      }
  }
}

// add bias, compute |h|^2 per row, rewrite Hp. one wave per row.
__global__ __launch_bounds__(256) void finish_proj(float* __restrict__ Hp,
                                                   const float* __restrict__ bp,
                                                   float* __restrict__ h2) {
  int wid = threadIdx.x >> 6, lane = threadIdx.x & 63;
  int row = blockIdx.x * 4 + wid;
  float* r = Hp + (size_t)row * NKF;
  float x0 = r[lane] + bp[lane];
  float x1 = r[lane + 64] + bp[lane + 64];
  float s = x0 * x0 + x1 * x1;
  for (int off = 32; off; off >>= 1) s += __shfl_down(s, off);
  r[lane] = x0;
  r[lane + 64] = x1;
  if (lane == 0) h2[row] = s;
}

// ==================== GP prep: z2, k_zz Cholesky, alpha ====================
__global__ __launch_bounds__(128) void gp_prep(const float* __restrict__ z,
                                               const float* __restrict__ vm,
                                               const float* __restrict__ ll,
                                               float* __restrict__ z2g,
                                               float* __restrict__ Lg,
                                               float* __restrict__ alphag) {
  int c = blockIdx.x, t = threadIdx.x;
  __shared__ float zc[NN * NKF];
  __shared__ float Amat[NN][NN + 1];
  __shared__ float z2s[NN], ys[NN], al[NN];
  const float* zcg = z + (size_t)c * NN * NKF;
  for (int i = t; i < NN * NKF; i += 128) zc[i] = zcg[i];
  __syncthreads();
  if (t < NN) {
    float s = 0.f;
    for (int k = 0; k < NKF; ++k) { float v = zc[t * NKF + k]; s += v * v; }
    z2s[t] = s;
    z2g[c * NN + t] = s;
  }
  __syncthreads();
  float inv2 = 0.5f * expf(-2.0f * ll[0]);  // 1/(2*ls^2)
  for (int e = t; e < NN * NN; e += 128) {
    int n = e / NN, m = e % NN;
    float d = 0.f;
    for (int k = 0; k < NKF; ++k) d += zc[n * NKF + k] * zc[m * NKF + k];
    float d2 = fmaxf(z2s[n] + z2s[m] - 2.0f * d, 0.0f);
    float v = expf(-d2 * inv2);
    if (n == m) v += 1e-4f;
    Amat[n][m] = v;
  }
  __syncthreads();
  // in-place Cholesky (lower)
  for (int j = 0; j < NN; ++j) {
    if (t == 0) {
      float s = Amat[j][j];
      for (int p = 0; p < j; ++p) s -= Amat[j][p] * Amat[j][p];
      Amat[j][j] = sqrtf(s);
    }
    __syncthreads();
    if (t > j && t < NN) {
      float s = Amat[t][j];
      for (int p = 0; p < j; ++p) s -= Amat[t][p] * Amat[j][p];
      Amat[t][j] = s / Amat[j][j];
    }
    __syncthreads();
  }
  if (t == 0) {
    const float* mc = vm + c * NN;
    for (int n = 0; n < NN; ++n) {
      float s = mc[n];
      for (int m = 0; m < n; ++m) s -= Amat[n][m] * ys[m];
      ys[n] = s / Amat[n][n];
    }
    for (int n = NN - 1; n >= 0; --n) {
      float s = ys[n];
      for (int m = n + 1; m < NN; ++m) s -= Amat[m][n] * al[m];
      al[n] = s / Amat[n][n];
    }
  }
  __syncthreads();
  for (int e = t; e < NN * NN; e += 128) {
    int n = e / NN, m = e % NN;
    Lg[(size_t)c * NN * NN + e] = (m <= n) ? Amat[n][m] : 0.0f;
  }
  if (t < NN) alphag[c * NN + t] = al[t];
}

// ==================== GP main: logits + uncertainty ====================
__global__ __launch_bounds__(256) void gp_main(const float* __restrict__ Hp,
                                               const float* __restrict__ h2g,
                                               const float* __restrict__ z,
                                               const float* __restrict__ z2g,
                                               const float* __restrict__ Lg,
                                               const float* __restrict__ alphag,
                                               const float* __restrict__ ll,
                                               float* __restrict__ logits,
                                               float* __restrict__ unc) {
  int c = blockIdx.y, b0 = blockIdx.x * 256, t = threadIdx.x;
  __shared__ float zc[NN * NKF];
  __shared__ float Ls[NN][NN + 1];
  __shared__ float z2s[NN], al[NN];
  __shared__ float hch[256][17];
  for (int i = t; i < NN * NKF; i += 256) zc[i] = z[(size_t)c * NN * NKF + i];
  for (int i = t; i < NN * NN; i += 256) {
    int n = i / NN, m = i % NN;
    Ls[n][m] = Lg[(size_t)c * NN * NN + i];
  }
  if (t < NN) { z2s[t] = z2g[c * NN + t]; al[t] = alphag[c * NN + t]; }
  float inv2 = 0.5f * expf(-2.0f * ll[0]);
  float acc[NN];
  #pragma unroll
  for (int n = 0; n < NN; ++n) acc[n] = 0.f;

  for (int kc = 0; kc < 8; ++kc) {
    int k0 = kc * 16;
    __syncthreads();
    #pragma unroll
    for (int p = 0; p < 16; ++p) {
      int rr = p * 16 + (t >> 4);
      int cc = t & 15;
      hch[rr][cc] = Hp[(size_t)(b0 + rr) * NKF + k0 + cc];
    }
    __syncthreads();
    float hk[16];
    #pragma unroll
    for (int kk = 0; kk < 16; ++kk) hk[kk] = hch[t][kk];
    #pragma unroll
    for (int n = 0; n < NN; ++n) {
      float s = acc[n];
      const float* zr = &zc[n * NKF + k0];
      #pragma unroll
      for (int kk = 0; kk < 16; ++kk) s += hk[kk] * zr[kk];
      acc[n] = s;
    }
  }

  float h2b = h2g[b0 + t];
  float lg = 0.f;
  #pragma unroll
  for (int n = 0; n < NN; ++n) {
    float d2 = fmaxf(h2b + z2s[n] - 2.0f * acc[n], 0.0f);
    float kx = expf(-d2 * inv2);
    acc[n] = kx;
    lg += kx * al[n];
  }
  logits[(size_t)(b0 + t) * NC + c] = lg;

  // forward triangular solve v = L^-1 k, in place
  float vsum = 0.f;
  #pragma unroll
  for (int n = 0; n < NN; ++n) {
    float s = acc[n];
    #pragma unroll
    for (int m = 0; m < NN; ++m) {
      if (m < n) s -= Ls[n][m] * acc[m];
    }
    s /= Ls[n][n];
    acc[n] = s;
    vsum += s * s;
  }
  atomicAdd(&unc[b0 + t], fmaxf(1.0f - vsum, 0.0f) * (1.0f / NC));
}

// ==================== softmax over classes ====================
__global__ __launch_bounds__(256) void softmax_k(const float* __restrict__ logits,
                                                 float* __restrict__ probs) {
  int wid = threadIdx.x >> 6, lane = threadIdx.x & 63;
  int row = blockIdx.x * 4 + wid;
  const float* lr = logits + (size_t)row * NC;
  float x[4];
  float mx = -1e30f;
  #pragma unroll
  for (int j = 0; j < 4; ++j) {
    int cix = lane + j * 64;
    x[j] = (cix < NC) ? lr[cix] : -1e30f;
    mx = fmaxf(mx, x[j]);
  }
  for (int off = 32; off; off >>= 1) mx = fmaxf(mx, __shfl_xor(mx, off));
  float s = 0.f;
  #pragma unroll
  for (int j = 0; j < 4; ++j) {
    int cix = lane + j * 64;
    float e = (cix < NC) ? expf(x[j] - mx) : 0.0f;
    x[j] = e; s += e;
  }
  for (int off = 32; off; off >>= 1) s += __shfl_xor(s, off);
  float inv = 1.0f / s;
  float* pr = probs + (size_t)row * NC;
  #pragma unroll
  for (int j = 0; j < 4; ++j) {
    int cix = lane + j * 64;
    if (cix < NC) pr[cix] = x[j] * inv;
  }
}

// ==================== launch ====================
extern "C" void kernel_launch(void* const* d_in, const int* in_sizes, int n_in,
                              void* d_out, int out_size, void* d_ws, size_t ws_size,
                              hipStream_t stream) {
  if (ws_size < WS_NEED) return;

  const float* X   = (const float*)d_in[0];
  const float* g1  = (const float*)d_in[1];
  const float* be1 = (const float*)d_in[2];
  const float* W1  = (const float*)d_in[3];
  const float* b1  = (const float*)d_in[4];
  const float* g2  = (const float*)d_in[5];
  const float* be2 = (const float*)d_in[6];
  const float* W2  = (const float*)d_in[7];
  const float* b2  = (const float*)d_in[8];
  const float* Wp  = (const float*)d_in[9];
  const float* bp  = (const float*)d_in[10];
  const float* ll  = (const float*)d_in[11];
  const float* Z   = (const float*)d_in[12];
  const float* VM  = (const float*)d_in[13];

  char* ws = (char*)d_ws;
  unsigned short* W1bf = (unsigned short*)(ws + OFF_W1BF);
  unsigned short* W2bf = (unsigned short*)(ws + OFF_W2BF);
  unsigned short* Wpbf = (unsigned short*)(ws + OFF_WPBF);
  unsigned short* Xbf  = (unsigned short*)(ws + OFF_XBF);
  unsigned short* H2bf = (unsigned short*)(ws + OFF_H2BF);
  unsigned short* H1bf = (unsigned short*)(ws + OFF_H1BF);
  unsigned short* H1n  = (unsigned short*)(ws + OFF_H1N);
  float* Hp    = (float*)(ws + OFF_HP);
  float* h2s   = (float*)(ws + OFF_H2S);
  float* vb    = (float*)(ws + OFF_PV);
  float* slots = vb + 3 * 2 * 2048;
  float* sinv  = (float*)(ws + OFF_SINV);
  float* z2g   = (float*)(ws + OFF_Z2);
  float* Lg    = (float*)(ws + OFF_LC);
  float* alphag= (float*)(ws + OFF_AL);

  // gram-phase aliases (dead once ln_e/gemm1/ln_h run)
  unsigned short* W1T  = (unsigned short*)(ws + GOFF_W1T);
  float*          G1   = (float*)(ws + GOFF_G1);
  unsigned short* Wp0  = (unsigned short*)(ws + GOFF_WP0);
  float*          Gp   = (float*)(ws + GOFF_GP);
  unsigned short* W2T  = (unsigned short*)(ws + GOFF_W2T);
  float*          G2   = (float*)(ws + GOFF_G2);

  float* out    = (float*)d_out;
  float* logits = out + (size_t)NB * NC;
  float* unc    = out + (size_t)2 * NB * NC;

  hipMemsetAsync(Hp, 0, (size_t)NB * NKF * 4, stream);
  hipMemsetAsync(unc, 0, (size_t)NB * 4, stream);

  // ---- spectral norms: Gram matrices (bf16 MFMA) + light power iteration ----
  cast_bf<<<dim3(128), 256, 0, stream>>>(Wp, Wp0, NKF * NH);
  transpose_cast<<<dim3(NE / 64, NH / 64), 256, 0, stream>>>(W1, W1T, NH, NE);
  transpose_cast<<<dim3(NH / 64, NH / 64), 256, 0, stream>>>(W2, W2T, NH, NH);
  gemm_nt<2><<<dim3(NE / 128, NE / 128), 256, 0, stream>>>(W1T, W1T, nullptr, (void*)G1, NE, NE, NH, 0);
  gemm_nt<2><<<dim3(NH / 128, NH / 128), 256, 0, stream>>>(W2T, W2T, nullptr, (void*)G2, NH, NH, NH, 0);
  gemm_nt<2><<<dim3(1, 1), 256, 0, stream>>>(Wp0, Wp0, nullptr, (void*)Gp, NKF, NKF, NH, 0);
  init_gram<<<dim3(1), 256, 0, stream>>>(vb, slots);
  for (int i = 0; i < NITER; ++i)
    gram_iter<<<dim3(368), 256, 0, stream>>>(G1, G2, Gp, vb, slots, i);
  finalize_sigma<<<dim3(1), 64, 0, stream>>>(slots, sinv);
  scale_weights<<<dim3(2944), 256, 0, stream>>>(W1, W2, Wp, sinv, W1bf, W2bf, Wpbf);

  // ---- MLP ----
  ln_e<<<dim3(NB / 4), 256, 0, stream>>>(X, g1, be1, Xbf);
  gemm_nt<0><<<dim3(NB / 128, NH / 128), 256, 0, stream>>>(Xbf, W1bf, b1, (void*)H1bf, NB, NH, NE, 0);
  ln_h<<<dim3(NB / 4), 256, 0, stream>>>(H1bf, g2, be2, H1n);
  gemm_nt<0><<<dim3(NB / 128, NH / 128), 256, 0, stream>>>(H1n, W2bf, b2, (void*)H2bf, NB, NH, NH, 0);
  gemm_nt<1><<<dim3(NB / 128, 1, 8), 256, 0, stream>>>(H2bf, Wpbf, bp, (void*)Hp, NB, NKF, NH, NH / 8);
  finish_proj<<<dim3(NB / 4), 256, 0, stream>>>(Hp, bp, h2s);

  // ---- GP head ----
  gp_prep<<<dim3(NC), 128, 0, stream>>>(Z, VM, ll, z2g, Lg, alphag);
  gp_main<<<dim3(NB / 256, NC), 256, 0, stream>>>(Hp, h2s, Z, z2g, Lg, alphag, ll, logits, unc);
  softmax_k<<<dim3(NB / 4), 256, 0, stream>>>(logits, out);
}

// Round 3
// 713.532 us; speedup vs baseline: 4.4979x; 1.9542x over previous
//
#include <hip/hip_runtime.h>
#include <cstdint>
#include <cstddef>

// ---------------- problem dims ----------------
#define NB 4096   // batch
#define NE 768    // in features
#define NH 2048   // hidden
#define NKF 128   // GP feature dim
#define NC 200    // classes
#define NN 20     // inducing points per class
#define NITER_R 10  // iterations on G^4  (== 40 on G)

typedef __attribute__((ext_vector_type(8))) short s16x8;
typedef __attribute__((ext_vector_type(8))) unsigned short u16x8;
typedef __attribute__((ext_vector_type(4))) unsigned short u16x4;
typedef __attribute__((ext_vector_type(4))) float f32x4;

__device__ inline unsigned short f2bf(float x) {
  unsigned u = __builtin_bit_cast(unsigned, x);
  u += 0x7fffu + ((u >> 16) & 1u);
  return (unsigned short)(u >> 16);
}
__device__ inline float bf2f(unsigned short h) {
  return __builtin_bit_cast(float, (unsigned)h << 16);
}
__device__ inline float gelu_exact(float x) {
  return x * 0.5f * (1.0f + erff(x * 0.70710678118654752f));
}

// ---------------- workspace layout (bytes) ----------------
constexpr size_t SZ_W1BF = (size_t)NH * NE * 2;
constexpr size_t SZ_W2BF = (size_t)NH * NH * 2;
constexpr size_t SZ_WPBF = (size_t)NKF * NH * 2;
constexpr size_t SZ_SLOT = (size_t)NB * NH * 2;  // 16.8 MB

constexpr size_t OFF_W1BF = 0;
constexpr size_t OFF_W2BF = OFF_W1BF + SZ_W1BF;
constexpr size_t OFF_WPBF = OFF_W2BF + SZ_W2BF;
constexpr size_t OFF_XBF  = OFF_WPBF + SZ_WPBF;  // slot A
constexpr size_t OFF_H2BF = OFF_XBF;             // gemm2 out (after gemm1 consumed Xbf)
constexpr size_t OFF_H1BF = OFF_XBF + SZ_SLOT;   // slot B
constexpr size_t OFF_H1N  = OFF_H1BF + SZ_SLOT;  // slot C
constexpr size_t OFF_HP   = OFF_H1N + SZ_SLOT;   // projection fp32 [NB][NKF]
constexpr size_t OFF_H2S  = OFF_HP + (size_t)NB * NKF * 4;  // |h|^2 per row
constexpr size_t OFF_PV   = OFF_H2S + (size_t)NB * 4;       // iter vectors + norm slots
constexpr size_t OFF_SINV = OFF_PV + (size_t)3 * 3 * 2048 * 4;
constexpr size_t OFF_Z2   = OFF_SINV + 256;
constexpr size_t OFF_LC   = OFF_Z2 + (size_t)NC * NN * 4;
constexpr size_t OFF_AL   = OFF_LC + (size_t)NC * NN * NN * 4;
constexpr size_t WS_NEED  = OFF_AL + (size_t)NC * NN * 4;

// --- gram-phase aliases (slot A / slot B; dead before ln_e / gemm1 write them) ---
constexpr size_t GOFF_W1T = OFF_XBF;                           // bf16 [768][2048]
constexpr size_t GOFF_WP0 = GOFF_W1T + (size_t)NE * NH * 2;    // bf16 [128][2048]
constexpr size_t GOFF_G1A = GOFF_WP0 + (size_t)NKF * NH * 2;   // bf16 768^2
constexpr size_t GOFF_G1B = GOFF_G1A + (size_t)NE * NE * 2;
constexpr size_t GOFF_GPA = GOFF_G1B + (size_t)NE * NE * 2;    // bf16 128^2
constexpr size_t GOFF_GPB = GOFF_GPA + (size_t)NKF * NKF * 2;
static_assert(GOFF_GPB + (size_t)NKF * NKF * 2 <= OFF_XBF + SZ_SLOT, "slotA overflow");
constexpr size_t GOFF_W2T = OFF_H1BF;                          // bf16 [2048][2048]
constexpr size_t GOFF_G2A = OFF_H1BF;                          // reuses W2T region AFTER gram gemm? no:
// W2T must stay alive while computing G2 = W2T*W2T^T. Put G2A in slot C.
constexpr size_t GOFF_G2C = OFF_H1N;                           // bf16 2048^2 (8.4MB of slot C)
constexpr size_t GOFF_G2D = OFF_H1N + (size_t)NH * NH * 2;     // bf16 2048^2 (second half)
// --- GP-phase aliases ---
constexpr size_t OFF_HPBF = OFF_H1BF;                          // bf16 [4096][128] (1MB)
constexpr size_t OFF_ZPAD = OFF_H1BF + (size_t)NB * NKF * 2;   // bf16 [200][32][128] (1.6MB)
constexpr size_t OFF_LGT  = OFF_H1N;                           // f32 [200][4096] logitsT (3.3MB)

// ==================== helpers ====================
__global__ __launch_bounds__(256) void cast_bf(const float* __restrict__ in,
                                               unsigned short* __restrict__ out, int n) {
  for (int i = blockIdx.x * 256 + threadIdx.x; i < n; i += gridDim.x * 256)
    out[i] = f2bf(in[i]);
}

// transpose+cast: fp32 [R][C] -> bf16 [C][R]
__global__ __launch_bounds__(256) void transpose_cast(const float* __restrict__ in,
                                                      unsigned short* __restrict__ out,
                                                      int R, int C) {
  __shared__ float tile[64][65];
  int c0 = blockIdx.x * 64, r0 = blockIdx.y * 64;
  int tx = threadIdx.x & 63, ty = threadIdx.x >> 6;
  #pragma unroll
  for (int j = 0; j < 16; ++j) {
    int r = ty + j * 4;
    tile[r][tx] = in[(size_t)(r0 + r) * C + c0 + tx];
  }
  __syncthreads();
  #pragma unroll
  for (int j = 0; j < 16; ++j) {
    int cc = ty + j * 4;
    out[(size_t)(c0 + cc) * R + r0 + tx] = f2bf(tile[tx][cc]);
  }
}

// ==================== unnormalized power iteration on G^4 (bf16) ====================
// vb: [3 mats][2 ping-pong][2048] f32 ; slots: [3][16] f32 (||v_i||^2)
__global__ __launch_bounds__(256) void init_gram(float* __restrict__ vb,
                                                 float* __restrict__ slots) {
  int t = threadIdx.x;
  for (int i = t; i < 3 * 2 * 2048; i += 256) vb[i] = 0.0f;
  for (int i = t; i < 48; i += 256) slots[i] = 0.0f;
  __syncthreads();
  const int kd[3] = {NE, NH, NKF};
  for (int m = 0; m < 3; ++m)
    for (int k = t; k < kd[m]; k += 256) vb[(m * 2) * 2048 + k] = 1.0f;
}

__global__ __launch_bounds__(256) void gram_iter(const unsigned short* __restrict__ G1q,
                                                 const unsigned short* __restrict__ G2q,
                                                 const unsigned short* __restrict__ Gpq,
                                                 float* __restrict__ vb,
                                                 float* __restrict__ slots, int iter) {
  int b = blockIdx.x, t = threadIdx.x;
  int m, r0, Kd;
  const unsigned short* G;
  if (b < 96)       { m = 0; G = G1q; Kd = NE;  r0 = b * 8; }
  else if (b < 352) { m = 1; G = G2q; Kd = NH;  r0 = (b - 96) * 8; }
  else              { m = 2; G = Gpq; Kd = NKF; r0 = (b - 352) * 8; }

  const float* vin = vb + ((size_t)m * 2 + (iter & 1)) * 2048;
  float* vout      = vb + ((size_t)m * 2 + ((iter + 1) & 1)) * 2048;

  __shared__ float vs[2048];
  for (int k = t; k < Kd; k += 256) vs[k] = vin[k];
  __syncthreads();

  int w = t >> 6, lane = t & 63;
  float nrm = 0.f;
  #pragma unroll
  for (int rr = 0; rr < 2; ++rr) {
    int row = r0 + w * 2 + rr;
    const unsigned short* gr = G + (size_t)row * Kd;
    float s = 0.f;
    for (int k0 = lane * 8; k0 < Kd; k0 += 512) {
      u16x8 u = *(const u16x8*)(gr + k0);
      #pragma unroll
      for (int q = 0; q < 8; ++q) s += bf2f(u[q]) * vs[k0 + q];
    }
    for (int off = 32; off; off >>= 1) s += __shfl_down(s, off);
    if (lane == 0) { vout[row] = s; nrm += s * s; }
  }
  if (lane == 0) atomicAdd(&slots[m * 16 + iter + 1], nrm);
}

__global__ void finalize_sigma(const float* __restrict__ slots, float* __restrict__ sinv) {
  int m = threadIdx.x;
  if (m < 3) {
    // iterated matrix = G^4/16; lam(G^4) = 16*||v10||/||v9|| ; sigma = lam^(1/8)
    float lam4 = 16.0f * sqrtf(slots[m * 16 + NITER_R] / slots[m * 16 + NITER_R - 1]);
    sinv[m] = powf(lam4, -0.125f);
  }
}

__global__ __launch_bounds__(256) void scale_weights(const float* __restrict__ W1,
                                                     const float* __restrict__ W2,
                                                     const float* __restrict__ Wp,
                                                     const float* __restrict__ sinv,
                                                     unsigned short* __restrict__ W1bf,
                                                     unsigned short* __restrict__ W2bf,
                                                     unsigned short* __restrict__ Wpbf) {
  const int n1 = NH * NE, n2 = NH * NH;
  float s0 = sinv[0], s1 = sinv[1], s2 = sinv[2];
  int base = blockIdx.x * 2048;
  for (int i = threadIdx.x; i < 2048; i += 256) {
    int g = base + i;
    if (g < n1) {
      W1bf[g] = f2bf(W1[g] * s0);
    } else if (g < n1 + n2) {
      int q = g - n1; W2bf[q] = f2bf(W2[q] * s1);
    } else {
      int q = g - n1 - n2; Wpbf[q] = f2bf(Wp[q] * s2);
    }
  }
}

// ==================== layernorms ====================
__global__ __launch_bounds__(256) void ln_e(const float* __restrict__ X,
                                            const float* __restrict__ g,
                                            const float* __restrict__ b,
                                            unsigned short* __restrict__ out) {
  int wid = threadIdx.x >> 6, lane = threadIdx.x & 63;
  int row = blockIdx.x * 4 + wid;
  const float* xr = X + (size_t)row * NE;
  float4 v[3];
  float s = 0.f, sq = 0.f;
  #pragma unroll
  for (int j = 0; j < 3; ++j) {
    v[j] = *(const float4*)(xr + j * 256 + lane * 4);
    s += v[j].x + v[j].y + v[j].z + v[j].w;
    sq += v[j].x * v[j].x + v[j].y * v[j].y + v[j].z * v[j].z + v[j].w * v[j].w;
  }
  for (int off = 32; off; off >>= 1) { s += __shfl_down(s, off); sq += __shfl_down(sq, off); }
  s = __shfl(s, 0); sq = __shfl(sq, 0);
  float mean = s * (1.0f / NE);
  float var = sq * (1.0f / NE) - mean * mean;
  float rstd = rsqrtf(var + 1e-5f);
  unsigned short* orow = out + (size_t)row * NE;
  #pragma unroll
  for (int j = 0; j < 3; ++j) {
    int e0 = j * 256 + lane * 4;
    float4 gg = *(const float4*)(g + e0);
    float4 bb = *(const float4*)(b + e0);
    u16x4 o;
    o[0] = f2bf((v[j].x - mean) * rstd * gg.x + bb.x);
    o[1] = f2bf((v[j].y - mean) * rstd * gg.y + bb.y);
    o[2] = f2bf((v[j].z - mean) * rstd * gg.z + bb.z);
    o[3] = f2bf((v[j].w - mean) * rstd * gg.w + bb.w);
    *(u16x4*)(orow + e0) = o;
  }
}

__global__ __launch_bounds__(256) void ln_h(const unsigned short* __restrict__ X,
                                            const float* __restrict__ g,
                                            const float* __restrict__ b,
                                            unsigned short* __restrict__ out) {
  int wid = threadIdx.x >> 6, lane = threadIdx.x & 63;
  int row = blockIdx.x * 4 + wid;
  const unsigned short* xr = X + (size_t)row * NH;
  float xv[32];
  float s = 0.f, sq = 0.f;
  #pragma unroll
  for (int j = 0; j < 4; ++j) {
    u16x8 u = *(const u16x8*)(xr + j * 512 + lane * 8);
    #pragma unroll
    for (int q = 0; q < 8; ++q) {
      float x = bf2f(u[q]);
      xv[j * 8 + q] = x; s += x; sq += x * x;
    }
  }
  for (int off = 32; off; off >>= 1) { s += __shfl_down(s, off); sq += __shfl_down(sq, off); }
  s = __shfl(s, 0); sq = __shfl(sq, 0);
  float mean = s * (1.0f / NH);
  float var = sq * (1.0f / NH) - mean * mean;
  float rstd = rsqrtf(var + 1e-5f);
  unsigned short* orow = out + (size_t)row * NH;
  #pragma unroll
  for (int j = 0; j < 4; ++j) {
    int e0 = j * 512 + lane * 8;
    float4 ga = *(const float4*)(g + e0);
    float4 gb = *(const float4*)(g + e0 + 4);
    float4 ba = *(const float4*)(b + e0);
    float4 bb = *(const float4*)(b + e0 + 4);
    u16x8 o;
    o[0] = f2bf((xv[j*8+0] - mean) * rstd * ga.x + ba.x);
    o[1] = f2bf((xv[j*8+1] - mean) * rstd * ga.y + ba.y);
    o[2] = f2bf((xv[j*8+2] - mean) * rstd * ga.z + ba.z);
    o[3] = f2bf((xv[j*8+3] - mean) * rstd * ga.w + ba.w);
    o[4] = f2bf((xv[j*8+4] - mean) * rstd * gb.x + bb.x);
    o[5] = f2bf((xv[j*8+5] - mean) * rstd * gb.y + bb.y);
    o[6] = f2bf((xv[j*8+6] - mean) * rstd * gb.z + bb.z);
    o[7] = f2bf((xv[j*8+7] - mean) * rstd * gb.w + bb.w);
    *(u16x8*)(orow + e0) = o;
  }
}

// ==================== bf16 MFMA GEMM (NT): C = A[M,K] * B[N,K]^T ====================
// EPI 0: gelu(acc+bias) -> bf16.  EPI 1: atomicAdd fp32 (split-K).  EPI 3: bf16 * cscale.
#define LSS 40

template <int EPI>
__global__ __launch_bounds__(256) void gemm_nt(const unsigned short* __restrict__ A,
                                               const unsigned short* __restrict__ Bm,
                                               const float* __restrict__ bias,
                                               void* __restrict__ Cout,
                                               int M, int Nn, int Kk, int KCH,
                                               float cscale) {
  __shared__ unsigned short As[128 * LSS];
  __shared__ unsigned short Bs[128 * LSS];
  int t = threadIdx.x;
  int bm0 = blockIdx.x * 128, bn0 = blockIdx.y * 128;
  int wid = t >> 6, lane = t & 63;
  int wm = wid >> 1, wn = wid & 1;

  int kb = 0, ke = Kk;
  if (KCH > 0) { kb = blockIdx.z * KCH; ke = kb + KCH; }

  f32x4 acc[4][4] = {};

  int lrow = t >> 2;
  int lk8 = (t & 3) * 8;
  const unsigned short* Ag = A + (size_t)(bm0 + lrow) * Kk + lk8;
  const unsigned short* Bg = Bm + (size_t)(bn0 + lrow) * Kk + lk8;

  int arow = wm * 64 + (lane & 15);
  int brow = wn * 64 + (lane & 15);
  int kfr = (lane >> 4) * 8;

  for (int ks = kb; ks < ke; ks += 32) {
    u16x8 ra0 = *(const u16x8*)(Ag + ks);
    u16x8 ra1 = *(const u16x8*)(Ag + (size_t)64 * Kk + ks);
    u16x8 rb0 = *(const u16x8*)(Bg + ks);
    u16x8 rb1 = *(const u16x8*)(Bg + (size_t)64 * Kk + ks);
    __syncthreads();
    *(u16x8*)&As[lrow * LSS + lk8] = ra0;
    *(u16x8*)&As[(lrow + 64) * LSS + lk8] = ra1;
    *(u16x8*)&Bs[lrow * LSS + lk8] = rb0;
    *(u16x8*)&Bs[(lrow + 64) * LSS + lk8] = rb1;
    __syncthreads();
    s16x8 af[4], bfr[4];
    #pragma unroll
    for (int i = 0; i < 4; ++i) af[i] = *(const s16x8*)&As[(arow + i * 16) * LSS + kfr];
    #pragma unroll
    for (int j = 0; j < 4; ++j) bfr[j] = *(const s16x8*)&Bs[(brow + j * 16) * LSS + kfr];
    #pragma unroll
    for (int i = 0; i < 4; ++i)
      #pragma unroll
      for (int j = 0; j < 4; ++j)
        acc[i][j] = __builtin_amdgcn_mfma_f32_16x16x32_bf16(af[i], bfr[j], acc[i][j], 0, 0, 0);
  }

  int crow0 = bm0 + wm * 64 + (lane >> 4) * 4;
  int ccol0 = bn0 + wn * 64 + (lane & 15);
  if constexpr (EPI == 0) {
    unsigned short* C = (unsigned short*)Cout;
    #pragma unroll
    for (int i = 0; i < 4; ++i) {
      #pragma unroll
      for (int j = 0; j < 4; ++j) {
        int col = ccol0 + j * 16;
        float bb = bias[col];
        #pragma unroll
        for (int r = 0; r < 4; ++r) {
          int row = crow0 + i * 16 + r;
          float x = acc[i][j][r] + bb;
          C[(size_t)row * Nn + col] = f2bf(gelu_exact(x));
        }
      }
    }
  } else if constexpr (EPI == 1) {
    float* C = (float*)Cout;
    #pragma unroll
    for (int i = 0; i < 4; ++i)
      #pragma unroll
      for (int j = 0; j < 4; ++j) {
        int col = ccol0 + j * 16;
        #pragma unroll
        for (int r = 0; r < 4; ++r) {
          int row = crow0 + i * 16 + r;
          atomicAdd(&C[(size_t)row * Nn + col], acc[i][j][r]);
        }
      }
  } else {
    unsigned short* C = (unsigned short*)Cout;
    #pragma unroll
    for (int i = 0; i < 4; ++i)
      #pragma unroll
      for (int j = 0; j < 4; ++j) {
        int col = ccol0 + j * 16;
        #pragma unroll
        for (int r = 0; r < 4; ++r) {
          int row = crow0 + i * 16 + r;
          C[(size_t)row * Nn + col] = f2bf(acc[i][j][r] * cscale);
        }
      }
  }
}

// add bias, |h|^2 per row, write bf16 h. one wave per row.
__global__ __launch_bounds__(256) void finish_proj(const float* __restrict__ Hp,
                                                   const float* __restrict__ bp,
                                                   unsigned short* __restrict__ Hpb,
                                                   float* __restrict__ h2) {
  int wid = threadIdx.x >> 6, lane = threadIdx.x & 63;
  int row = blockIdx.x * 4 + wid;
  const float* r = Hp + (size_t)row * NKF;
  float x0 = r[lane] + bp[lane];
  float x1 = r[lane + 64] + bp[lane + 64];
  float s = x0 * x0 + x1 * x1;
  for (int off = 32; off; off >>= 1) s += __shfl_down(s, off);
  unsigned short* hb = Hpb + (size_t)row * NKF;
  hb[lane] = f2bf(x0);
  hb[lane + 64] = f2bf(x1);
  if (lane == 0) h2[row] = s;
}

// ==================== GP prep: z2, k_zz Cholesky, alpha, z bf16 padded ====================
__global__ __launch_bounds__(128) void gp_prep(const float* __restrict__ z,
                                               const float* __restrict__ vm,
                                               const float* __restrict__ ll,
                                               float* __restrict__ z2g,
                                               float* __restrict__ Lg,
                                               float* __restrict__ alphag,
                                               unsigned short* __restrict__ zpad) {
  int c = blockIdx.x, t = threadIdx.x;
  __shared__ float zc[NN * NKF];
  __shared__ float Amat[NN][NN + 1];
  __shared__ float z2s[NN], ys[NN], al[NN];
  const float* zcg = z + (size_t)c * NN * NKF;
  for (int i = t; i < NN * NKF; i += 128) zc[i] = zcg[i];
  __syncthreads();
  if (t < NN) {
    float s = 0.f;
    for (int k = 0; k < NKF; ++k) { float v = zc[t * NKF + k]; s += v * v; }
    z2s[t] = s;
    z2g[c * NN + t] = s;
  }
  __syncthreads();
  float inv2 = 0.5f * expf(-2.0f * ll[0]);
  for (int e = t; e < NN * NN; e += 128) {
    int n = e / NN, m = e % NN;
    float d = 0.f;
    for (int k = 0; k < NKF; ++k) d += zc[n * NKF + k] * zc[m * NKF + k];
    float d2 = fmaxf(z2s[n] + z2s[m] - 2.0f * d, 0.0f);
    float v = expf(-d2 * inv2);
    if (n == m) v += 1e-4f;
    Amat[n][m] = v;
  }
  __syncthreads();
  for (int j = 0; j < NN; ++j) {
    if (t == 0) {
      float s = Amat[j][j];
      for (int p = 0; p < j; ++p) s -= Amat[j][p] * Amat[j][p];
      Amat[j][j] = sqrtf(s);
    }
    __syncthreads();
    if (t > j && t < NN) {
      float s = Amat[t][j];
      for (int p = 0; p < j; ++p) s -= Amat[t][p] * Amat[j][p];
      Amat[t][j] = s / Amat[j][j];
    }
    __syncthreads();
  }
  if (t == 0) {
    const float* mc = vm + c * NN;
    for (int n = 0; n < NN; ++n) {
      float s = mc[n];
      for (int m = 0; m < n; ++m) s -= Amat[n][m] * ys[m];
      ys[n] = s / Amat[n][n];
    }
    for (int n = NN - 1; n >= 0; --n) {
      float s = ys[n];
      for (int m = n + 1; m < NN; ++m) s -= Amat[m][n] * al[m];
      al[n] = s / Amat[n][n];
    }
  }
  __syncthreads();
  for (int e = t; e < NN * NN; e += 128) {
    int n = e / NN, m = e % NN;
    Lg[(size_t)c * NN * NN + e] = (m <= n) ? Amat[n][m] : 0.0f;
  }
  if (t < NN) alphag[c * NN + t] = al[t];
  unsigned short* zp = zpad + (size_t)c * 32 * NKF;
  for (int i = t; i < 32 * NKF; i += 128) {
    int n = i >> 7;
    zp[i] = (n < NN) ? f2bf(zc[i & (NN * NKF - 1) < 0 ? 0 : (n * NKF + (i & 127))]) : (unsigned short)0;
  }
}

// ==================== GP main: MFMA k_xz + logits + uncertainty ====================
__global__ __launch_bounds__(256) void gp_main(const unsigned short* __restrict__ Hpb,
                                               const float* __restrict__ h2g,
                                               const unsigned short* __restrict__ zpad,
                                               const float* __restrict__ z2g,
                                               const float* __restrict__ Lg,
                                               const float* __restrict__ alphag,
                                               const float* __restrict__ ll,
                                               float* __restrict__ logitsT,
                                               float* __restrict__ unc) {
  int c = blockIdx.y, b0 = blockIdx.x * 256, t = threadIdx.x;
  int w = t >> 6, lane = t & 63;
  __shared__ unsigned short zs[32 * 136];
  __shared__ float kxs[256][21];
  __shared__ float Ls[NN][21];
  __shared__ float z2s[32], al[NN], ht2[256];

  {
    const unsigned short* zp = zpad + (size_t)c * 32 * NKF;
    int n = t >> 3, k = (t & 7) * 16;
    u16x8 a = *(const u16x8*)(zp + n * NKF + k);
    u16x8 b = *(const u16x8*)(zp + n * NKF + k + 8);
    *(u16x8*)&zs[n * 136 + k] = a;
    *(u16x8*)&zs[n * 136 + k + 8] = b;
  }
  for (int i = t; i < NN * NN; i += 256) Ls[i / NN][i % NN] = Lg[(size_t)c * NN * NN + i];
  if (t < 32) z2s[t] = (t < NN) ? z2g[c * NN + t] : 0.f;
  if (t < NN) al[t] = alphag[c * NN + t];
  ht2[t] = h2g[b0 + t];
  float inv2 = 0.5f * __expf(-2.0f * ll[0]);
  __syncthreads();

  f32x4 acc[4][2] = {};
  const unsigned short* hbase = Hpb + (size_t)(b0 + w * 64 + (lane & 15)) * NKF + (lane >> 4) * 8;
  #pragma unroll
  for (int ks = 0; ks < 4; ++ks) {
    s16x8 af[4], bfr[2];
    #pragma unroll
    for (int i = 0; i < 4; ++i) af[i] = *(const s16x8*)(hbase + (size_t)i * 16 * NKF + ks * 32);
    #pragma unroll
    for (int j = 0; j < 2; ++j)
      bfr[j] = *(const s16x8*)&zs[(j * 16 + (lane & 15)) * 136 + ks * 32 + (lane >> 4) * 8];
    #pragma unroll
    for (int i = 0; i < 4; ++i)
      #pragma unroll
      for (int j = 0; j < 2; ++j)
        acc[i][j] = __builtin_amdgcn_mfma_f32_16x16x32_bf16(af[i], bfr[j], acc[i][j], 0, 0, 0);
  }

  #pragma unroll
  for (int i = 0; i < 4; ++i)
    #pragma unroll
    for (int j = 0; j < 2; ++j) {
      int col = j * 16 + (lane & 15);
      #pragma unroll
      for (int r = 0; r < 4; ++r) {
        int rl = w * 64 + i * 16 + (lane >> 4) * 4 + r;
        float d2 = fmaxf(ht2[rl] + z2s[col] - 2.0f * acc[i][j][r], 0.0f);
        float kx = __expf(-d2 * inv2);
        if (col < NN) kxs[rl][col] = kx;
      }
    }
  __syncthreads();

  float kr[NN];
  #pragma unroll
  for (int n = 0; n < NN; ++n) kr[n] = kxs[t][n];
  float lg = 0.f;
  #pragma unroll
  for (int n = 0; n < NN; ++n) lg += kr[n] * al[n];
  logitsT[(size_t)c * NB + b0 + t] = lg;

  float vsum = 0.f;
  #pragma unroll
  for (int n = 0; n < NN; ++n) {
    float s = kr[n];
    #pragma unroll
    for (int m = 0; m < NN; ++m)
      if (m < n) s -= Ls[n][m] * kr[m];
    s /= Ls[n][n];
    kr[n] = s;
    vsum += s * s;
  }
  atomicAdd(&unc[b0 + t], fmaxf(1.0f - vsum, 0.0f) * (1.0f / NC));
}

// ==================== transpose + softmax: logitsT [C][B] -> probs/logits [B][C] ====================
__global__ __launch_bounds__(256) void softmax_t(const float* __restrict__ logitsT,
                                                 float* __restrict__ probs,
                                                 float* __restrict__ logits_out) {
  int b0 = blockIdx.x * 64, t = threadIdx.x;
  __shared__ float tile[NC][65];
  __shared__ float redmx[4][64], redsm[4][64], mxs[64], invs[64];
  for (int i = t; i < NC * 64; i += 256) {
    int cc = i >> 6, j = i & 63;
    tile[cc][j] = logitsT[(size_t)cc * NB + b0 + j];
  }
  __syncthreads();
  int j = t & 63, p = t >> 6;
  float mx = -1e30f;
  for (int cc = p * 50; cc < p * 50 + 50; ++cc) mx = fmaxf(mx, tile[cc][j]);
  redmx[p][j] = mx;
  __syncthreads();
  if (p == 0) mxs[j] = fmaxf(fmaxf(redmx[0][j], redmx[1][j]), fmaxf(redmx[2][j], redmx[3][j]));
  __syncthreads();
  float m2 = mxs[j], sm = 0.f;
  for (int cc = p * 50; cc < p * 50 + 50; ++cc) sm += __expf(tile[cc][j] - m2);
  redsm[p][j] = sm;
  __syncthreads();
  if (p == 0) invs[j] = 1.0f / (redsm[0][j] + redsm[1][j] + redsm[2][j] + redsm[3][j]);
  __syncthreads();
  for (int i = t; i < 64 * NC; i += 256) {
    int jj = i / NC, cc = i % NC;
    float lv = tile[cc][jj];
    size_t o = (size_t)(b0 + jj) * NC + cc;
    probs[o] = __expf(lv - mxs[jj]) * invs[jj];
    logits_out[o] = lv;
  }
}

// ==================== launch ====================
extern "C" void kernel_launch(void* const* d_in, const int* in_sizes, int n_in,
                              void* d_out, int out_size, void* d_ws, size_t ws_size,
                              hipStream_t stream) {
  if (ws_size < WS_NEED) return;

  const float* X   = (const float*)d_in[0];
  const float* g1  = (const float*)d_in[1];
  const float* be1 = (const float*)d_in[2];
  const float* W1  = (const float*)d_in[3];
  const float* b1  = (const float*)d_in[4];
  const float* g2  = (const float*)d_in[5];
  const float* be2 = (const float*)d_in[6];
  const float* W2  = (const float*)d_in[7];
  const float* b2  = (const float*)d_in[8];
  const float* Wp  = (const float*)d_in[9];
  const float* bp  = (const float*)d_in[10];
  const float* ll  = (const float*)d_in[11];
  const float* Z   = (const float*)d_in[12];
  const float* VM  = (const float*)d_in[13];

  char* ws = (char*)d_ws;
  unsigned short* W1bf = (unsigned short*)(ws + OFF_W1BF);
  unsigned short* W2bf = (unsigned short*)(ws + OFF_W2BF);
  unsigned short* Wpbf = (unsigned short*)(ws + OFF_WPBF);
  unsigned short* Xbf  = (unsigned short*)(ws + OFF_XBF);
  unsigned short* H2bf = (unsigned short*)(ws + OFF_H2BF);
  unsigned short* H1bf = (unsigned short*)(ws + OFF_H1BF);
  unsigned short* H1n  = (unsigned short*)(ws + OFF_H1N);
  float* Hp    = (float*)(ws + OFF_HP);
  float* h2s   = (float*)(ws + OFF_H2S);
  float* vb    = (float*)(ws + OFF_PV);
  float* slots = vb + 3 * 2 * 2048;
  float* sinv  = (float*)(ws + OFF_SINV);
  float* z2g   = (float*)(ws + OFF_Z2);
  float* Lg    = (float*)(ws + OFF_LC);
  float* alphag= (float*)(ws + OFF_AL);

  // gram-phase aliases
  unsigned short* W1T = (unsigned short*)(ws + GOFF_W1T);
  unsigned short* Wp0 = (unsigned short*)(ws + GOFF_WP0);
  unsigned short* G1a = (unsigned short*)(ws + GOFF_G1A);
  unsigned short* G1b = (unsigned short*)(ws + GOFF_G1B);
  unsigned short* Gpa = (unsigned short*)(ws + GOFF_GPA);
  unsigned short* Gpb = (unsigned short*)(ws + GOFF_GPB);
  unsigned short* W2T = (unsigned short*)(ws + GOFF_W2T);
  unsigned short* G2c = (unsigned short*)(ws + GOFF_G2C);
  unsigned short* G2d = (unsigned short*)(ws + GOFF_G2D);
  // GP-phase aliases
  unsigned short* Hpb  = (unsigned short*)(ws + OFF_HPBF);
  unsigned short* zpad = (unsigned short*)(ws + OFF_ZPAD);
  float* logitsT = (float*)(ws + OFF_LGT);

  float* out    = (float*)d_out;
  float* logits = out + (size_t)NB * NC;
  float* unc    = out + (size_t)2 * NB * NC;

  hipMemsetAsync(Hp, 0, (size_t)NB * NKF * 4, stream);
  hipMemsetAsync(unc, 0, (size_t)NB * 4, stream);

  // ---- spectral norms: G (bf16) -> G^2 -> G^4/16, then 10 unnormalized iters ----
  cast_bf<<<dim3(128), 256, 0, stream>>>(Wp, Wp0, NKF * NH);
  transpose_cast<<<dim3(NE / 64, NH / 64), 256, 0, stream>>>(W1, W1T, NH, NE);
  transpose_cast<<<dim3(NH / 64, NH / 64), 256, 0, stream>>>(W2, W2T, NH, NH);
  // G (bf16 out): G1a = W1T*W1T^T ; G2c = W2T*W2T^T ; Gpa = Wp0*Wp0^T
  gemm_nt<3><<<dim3(NE / 128, NE / 128), 256, 0, stream>>>(W1T, W1T, nullptr, (void*)G1a, NE, NE, NH, 0, 1.0f);
  gemm_nt<3><<<dim3(NH / 128, NH / 128), 256, 0, stream>>>(W2T, W2T, nullptr, (void*)G2c, NH, NH, NH, 0, 1.0f);
  gemm_nt<3><<<dim3(1, 1), 256, 0, stream>>>(Wp0, Wp0, nullptr, (void*)Gpa, NKF, NKF, NH, 0, 1.0f);
  // G^2
  gemm_nt<3><<<dim3(NE / 128, NE / 128), 256, 0, stream>>>(G1a, G1a, nullptr, (void*)G1b, NE, NE, NE, 0, 1.0f);
  gemm_nt<3><<<dim3(NH / 128, NH / 128), 256, 0, stream>>>(G2c, G2c, nullptr, (void*)G2d, NH, NH, NH, 0, 1.0f);
  gemm_nt<3><<<dim3(1, 1), 256, 0, stream>>>(Gpa, Gpa, nullptr, (void*)Gpb, NKF, NKF, NKF, 0, 1.0f);
  // G^4 / 16
  gemm_nt<3><<<dim3(NE / 128, NE / 128), 256, 0, stream>>>(G1b, G1b, nullptr, (void*)G1a, NE, NE, NE, 0, 0.0625f);
  gemm_nt<3><<<dim3(NH / 128, NH / 128), 256, 0, stream>>>(G2d, G2d, nullptr, (void*)G2c, NH, NH, NH, 0, 0.0625f);
  gemm_nt<3><<<dim3(1, 1), 256, 0, stream>>>(Gpb, Gpb, nullptr, (void*)Gpa, NKF, NKF, NKF, 0, 0.0625f);
  init_gram<<<dim3(1), 256, 0, stream>>>(vb, slots);
  for (int i = 0; i < NITER_R; ++i)
    gram_iter<<<dim3(368), 256, 0, stream>>>(G1a, G2c, Gpa, vb, slots, i);
  finalize_sigma<<<dim3(1), 64, 0, stream>>>(slots, sinv);
  scale_weights<<<dim3(2944), 256, 0, stream>>>(W1, W2, Wp, sinv, W1bf, W2bf, Wpbf);

  // ---- MLP ----
  ln_e<<<dim3(NB / 4), 256, 0, stream>>>(X, g1, be1, Xbf);
  gemm_nt<0><<<dim3(NB / 128, NH / 128), 256, 0, stream>>>(Xbf, W1bf, b1, (void*)H1bf, NB, NH, NE, 0, 1.0f);
  ln_h<<<dim3(NB / 4), 256, 0, stream>>>(H1bf, g2, be2, H1n);
  gemm_nt<0><<<dim3(NB / 128, NH / 128), 256, 0, stream>>>(H1n, W2bf, b2, (void*)H2bf, NB, NH, NH, 0, 1.0f);
  gemm_nt<1><<<dim3(NB / 128, 1, 8), 256, 0, stream>>>(H2bf, Wpbf, bp, (void*)Hp, NB, NKF, NH, NH / 8, 1.0f);
  finish_proj<<<dim3(NB / 4), 256, 0, stream>>>(Hp, bp, Hpb, h2s);

  // ---- GP head ----
  gp_prep<<<dim3(NC), 128, 0, stream>>>(Z, VM, ll, z2g, Lg, alphag, zpad);
  gp_main<<<dim3(NB / 256, NC), 256, 0, stream>>>(Hpb, h2s, zpad, z2g, Lg, alphag, ll, logitsT, unc);
  softmax_t<<<dim3(NB / 64), 256, 0, stream>>>(logitsT, out, logits);
}